// Round 1
// baseline (5203.099 us; speedup 1.0000x reference)
//
#include <hip/hip_runtime.h>
#include <math.h>

#define NBINS 131072

// ---- order-preserving float<->u32 encoding for atomicMax on floats ----
__device__ __forceinline__ unsigned encf(float f) {
    unsigned u = __float_as_uint(f);
    return (u & 0x80000000u) ? ~u : (u | 0x80000000u);
}
__device__ __forceinline__ float decf(unsigned u) {
    return (u & 0x80000000u) ? __uint_as_float(u & 0x7FFFFFFFu) : __uint_as_float(~u);
}

// K1: per-bin count + min-index (head) over all N points. c0 = code0 >> 3 < 2^17.
__global__ void k_hist(const int* __restrict__ scode, int* head_min, int* cnt, int N) {
    int i = blockIdx.x * blockDim.x + threadIdx.x;
    if (i >= N) return;
    int c0 = scode[i] >> 3;
    atomicMin(&head_min[c0], i);
    atomicAdd(&cnt[c0], 1);
}

// K2: single-block scan over 131072 presence flags -> rank per bin, compact heads/counts.
__global__ void k_scan_compact(const int* __restrict__ cnt, const int* __restrict__ head_min,
                               int* rank, int* heads, int* countsC) {
    __shared__ int part[1024];
    int t = threadIdx.x;
    const int per = NBINS / 1024;  // 128
    int base = t * per;
    int s = 0;
    for (int j = 0; j < per; j++) s += (cnt[base + j] > 0);
    part[t] = s;
    __syncthreads();
    if (t == 0) {
        int run = 0;
        for (int i = 0; i < 1024; i++) { int v = part[i]; part[i] = run; run += v; }
    }
    __syncthreads();
    int run = part[t];
    for (int j = 0; j < per; j++) {
        int v = base + j;
        if (cnt[v] > 0) {
            rank[v] = run;
            heads[run] = head_min[v];
            countsC[run] = cnt[v];
            run++;
        }
    }
}

// K3: per-point cluster id output (+ coord sums via atomics).
__global__ void k_points(const int* __restrict__ scode, const int* __restrict__ rank,
                         const float* __restrict__ coord, float* __restrict__ cluster_out,
                         float* __restrict__ coordsum, int N) {
    int i = blockIdx.x * blockDim.x + threadIdx.x;
    if (i >= N) return;
    int m = rank[scode[i] >> 3];
    cluster_out[i] = (float)m;
    atomicAdd(&coordsum[m * 3 + 0], coord[(size_t)i * 3 + 0]);
    atomicAdd(&coordsum[m * 3 + 1], coord[(size_t)i * 3 + 1]);
    atomicAdd(&coordsum[m * 3 + 2], coord[(size_t)i * 3 + 2]);
}

// K4: per-cluster small outputs + histogram of c1 buckets for the row-1 sort.
__global__ void k_clusters(const int* __restrict__ scode, const int* __restrict__ batch,
                           const int* __restrict__ grid_coord, const int* __restrict__ heads,
                           const int* __restrict__ countsC, const float* __restrict__ coordsum,
                           float* __restrict__ coord_p, float* __restrict__ grid_p,
                           float* __restrict__ code_h, float* __restrict__ order,
                           float* __restrict__ inverse, float* __restrict__ batch_p,
                           int* hist2, int M, int N) {
    int m = blockIdx.x * blockDim.x + threadIdx.x;
    if (m >= M) return;
    int h = heads[m];
    float invc = 1.0f / (float)countsC[m];
    coord_p[m * 3 + 0] = coordsum[m * 3 + 0] * invc;
    coord_p[m * 3 + 1] = coordsum[m * 3 + 1] * invc;
    coord_p[m * 3 + 2] = coordsum[m * 3 + 2] * invc;
    grid_p[m * 3 + 0] = (float)(grid_coord[(size_t)h * 3 + 0] >> 1);
    grid_p[m * 3 + 1] = (float)(grid_coord[(size_t)h * 3 + 1] >> 1);
    grid_p[m * 3 + 2] = (float)(grid_coord[(size_t)h * 3 + 2] >> 1);
    int c1 = scode[N + h] >> 3;
    code_h[m] = (float)(scode[h] >> 3);
    code_h[M + m] = (float)c1;
    // row 0 of code_h is strictly increasing in m -> order/inverse row 0 are identity
    order[m] = (float)m;
    inverse[m] = (float)m;
    batch_p[m] = (float)batch[h];
    atomicAdd(&hist2[c1 >> 10], 1);
}

// K5: in-place exclusive scan of the 2^17 bucket histogram (single block).
__global__ void k_scan_excl(int* a) {
    __shared__ int part[1024];
    int t = threadIdx.x;
    const int per = NBINS / 1024;
    int base = t * per;
    int s = 0;
    for (int j = 0; j < per; j++) s += a[base + j];
    part[t] = s;
    __syncthreads();
    if (t == 0) {
        int run = 0;
        for (int i = 0; i < 1024; i++) { int v = part[i]; part[i] = run; run += v; }
    }
    __syncthreads();
    int run = part[t];
    for (int j = 0; j < per; j++) { int v = a[base + j]; a[base + j] = run; run += v; }
}

// K6: scatter (c1_low<<17 | m) keys into buckets (bucket = c1>>10).
__global__ void k_keys(const int* __restrict__ scode, const int* __restrict__ heads,
                       const int* __restrict__ start, int* fill2, int* keys, int M, int N) {
    int m = blockIdx.x * blockDim.x + threadIdx.x;
    if (m >= M) return;
    int c1 = scode[N + heads[m]] >> 3;
    int b = c1 >> 10;
    int pos = start[b] + atomicAdd(&fill2[b], 1);
    keys[pos] = ((c1 & 1023) << 17) | m;
}

// K7: per-bucket insertion sort (bucket sizes ~Poisson(1), max ~10).
// Sorting by (c1_low, m) within (c1_high) buckets == stable argsort by c1.
__global__ void k_bsort(int* keys, const int* __restrict__ start, const int* __restrict__ sz) {
    int b = blockIdx.x * blockDim.x + threadIdx.x;
    if (b >= NBINS) return;
    int s = start[b], n = sz[b];
    for (int i = 1; i < n; i++) {
        int k = keys[s + i];
        int j = i - 1;
        while (j >= 0 && keys[s + j] > k) { keys[s + j + 1] = keys[s + j]; j--; }
        keys[s + j + 1] = k;
    }
}

// K8: extract order row 1 and its inverse permutation.
__global__ void k_orders(const int* __restrict__ keys, float* __restrict__ order1,
                         float* __restrict__ inverse1, int M) {
    int i = blockIdx.x * blockDim.x + threadIdx.x;
    if (i >= M) return;
    int m = keys[i] & 0x1FFFF;
    order1[i] = (float)m;
    inverse1[m] = (float)i;
}

// K9: fp32 GEMM (proj = feat @ W^T + b) fused with segment-max scatter via encoded atomicMax.
// Block: 64 points x 256 channels (4 serial 64-channel tiles), 256 threads, 4x4 register block.
__global__ __launch_bounds__(256) void k_gemm_max(
    const float* __restrict__ feat, const float* __restrict__ W, const float* __restrict__ bias,
    const int* __restrict__ scode, const int* __restrict__ rank,
    unsigned* __restrict__ xout, int N) {
    __shared__ float sf[64][132];  // +4 pad: 2-way LDS conflict max (free), keeps 16B align
    __shared__ float sw[64][132];
    __shared__ int scid[64];
    int t = threadIdx.x;
    size_t rowbase = (size_t)blockIdx.x * 64;
    // stage 64x128 feat tile (2048 float4, 8 per thread, coalesced)
#pragma unroll
    for (int j = 0; j < 8; j++) {
        int idx = t + 256 * j;
        int r = idx >> 5, c4 = idx & 31;
        float4 v = *(const float4*)(feat + (rowbase + r) * 128 + c4 * 4);
        *(float4*)&sf[r][c4 * 4] = v;
    }
    if (t < 64) {
        int i = (int)rowbase + t;
        scid[t] = rank[scode[i] >> 3];
    }
    int pg = t & 15, cg = t >> 4;
    for (int ct = 0; ct < 4; ct++) {
        __syncthreads();  // protect sw (and sf/scid on first pass)
#pragma unroll
        for (int j = 0; j < 8; j++) {
            int idx = t + 256 * j;
            int r = idx >> 5, c4 = idx & 31;
            float4 v = *(const float4*)(W + (size_t)(ct * 64 + r) * 128 + c4 * 4);
            *(float4*)&sw[r][c4 * 4] = v;
        }
        __syncthreads();
        float acc[4][4] = {};
#pragma unroll
        for (int kc = 0; kc < 32; kc++) {
            float4 fv[4], wv[4];
#pragma unroll
            for (int p = 0; p < 4; p++) fv[p] = *(const float4*)&sf[pg * 4 + p][kc * 4];
#pragma unroll
            for (int c = 0; c < 4; c++) wv[c] = *(const float4*)&sw[cg * 4 + c][kc * 4];
#pragma unroll
            for (int p = 0; p < 4; p++)
#pragma unroll
                for (int c = 0; c < 4; c++)
                    acc[p][c] += fv[p].x * wv[c].x + fv[p].y * wv[c].y +
                                 fv[p].z * wv[c].z + fv[p].w * wv[c].w;
        }
#pragma unroll
        for (int p = 0; p < 4; p++) {
            int cid = scid[pg * 4 + p];
#pragma unroll
            for (int c = 0; c < 4; c++) {
                int ch = ct * 64 + cg * 4 + c;
                float val = acc[p][c] + bias[ch];
                atomicMax(&xout[(size_t)cid * 256 + ch], encf(val));
            }
        }
    }
}

// K10: in-place LayerNorm + exact GELU over each cluster row (decode encoded maxes first).
__global__ __launch_bounds__(256) void k_ln_gelu(unsigned* __restrict__ x,
                                                 const float* __restrict__ gamma,
                                                 const float* __restrict__ beta, int M) {
    int row = blockIdx.x;
    if (row >= M) return;
    int t = threadIdx.x;
    float v = decf(x[(size_t)row * 256 + t]);
    float s = v, s2 = v * v;
#pragma unroll
    for (int off = 32; off > 0; off >>= 1) {
        s += __shfl_down(s, off);
        s2 += __shfl_down(s2, off);
    }
    __shared__ float red[8];
    int wave = t >> 6, lane = t & 63;
    if (lane == 0) { red[wave] = s; red[4 + wave] = s2; }
    __syncthreads();
    if (t == 0) {
        red[0] = red[0] + red[1] + red[2] + red[3];
        red[4] = red[4] + red[5] + red[6] + red[7];
    }
    __syncthreads();
    float mean = red[0] * (1.0f / 256.0f);
    float var = red[4] * (1.0f / 256.0f) - mean * mean;
    float xn = (v - mean) * rsqrtf(var + 1e-5f) * gamma[t] + beta[t];
    float g = 0.5f * xn * (1.0f + erff(xn * 0.70710678118654752f));
    ((float*)x)[(size_t)row * 256 + t] = g;
}

extern "C" void kernel_launch(void* const* d_in, const int* in_sizes, int n_in,
                              void* d_out, int out_size, void* d_ws, size_t ws_size,
                              hipStream_t stream) {
    const float* feat = (const float*)d_in[0];
    const float* coord = (const float*)d_in[1];
    const int* grid_coord = (const int*)d_in[2];
    const int* scode = (const int*)d_in[3];   // int32 (JAX x64-off truncation), shape (2,N)
    const int* batch = (const int*)d_in[4];
    const float* W = (const float*)d_in[6];
    const float* bias = (const float*)d_in[7];
    const float* gamma = (const float*)d_in[8];
    const float* beta = (const float*)d_in[9];

    int N = in_sizes[0] / 128;                 // C_IN = 128
    int M = (out_size - N) / 269;              // 269 = 256+3+3+2+2+2+1 per-cluster elems

    float* out = (float*)d_out;
    float* x_out = out;                        // M*256
    float* coord_p = x_out + (size_t)M * 256;  // 3M
    float* grid_p = coord_p + (size_t)3 * M;   // 3M
    float* code_h = grid_p + (size_t)3 * M;    // 2M
    float* order = code_h + (size_t)2 * M;     // 2M
    float* inverse = order + (size_t)2 * M;    // 2M
    float* cluster = inverse + (size_t)2 * M;  // N
    float* batch_p = cluster + (size_t)N;      // M

    int* head_min = (int*)d_ws;        // NBINS
    int* cnt = head_min + NBINS;       // NBINS
    int* rank = cnt + NBINS;           // NBINS
    int* hist2 = rank + NBINS;         // NBINS
    int* fill2 = hist2 + NBINS;        // NBINS
    int* heads = fill2 + NBINS;        // M
    int* countsC = heads + M;          // M
    float* coordsum = (float*)(countsC + M);  // 3M
    int* keys = (int*)(coordsum + (size_t)3 * M);  // M

    hipMemsetAsync(head_min, 0x7F, (size_t)NBINS * sizeof(int), stream);      // "+inf" index
    hipMemsetAsync(cnt, 0, (size_t)4 * NBINS * sizeof(int), stream);          // cnt,rank,hist2,fill2
    hipMemsetAsync(coordsum, 0, (size_t)3 * M * sizeof(float), stream);
    hipMemsetAsync(x_out, 0, (size_t)M * 256 * sizeof(float), stream);        // encoded -inf

    k_hist<<<(N + 255) / 256, 256, 0, stream>>>(scode, head_min, cnt, N);
    k_scan_compact<<<1, 1024, 0, stream>>>(cnt, head_min, rank, heads, countsC);
    k_points<<<(N + 255) / 256, 256, 0, stream>>>(scode, rank, coord, cluster, coordsum, N);
    k_clusters<<<(M + 255) / 256, 256, 0, stream>>>(scode, batch, grid_coord, heads, countsC,
                                                    coordsum, coord_p, grid_p, code_h, order,
                                                    inverse, batch_p, hist2, M, N);
    k_scan_excl<<<1, 1024, 0, stream>>>(hist2);
    k_keys<<<(M + 255) / 256, 256, 0, stream>>>(scode, heads, hist2, fill2, keys, M, N);
    k_bsort<<<NBINS / 256, 256, 0, stream>>>(keys, hist2, fill2);
    k_orders<<<(M + 255) / 256, 256, 0, stream>>>(keys, order + M, inverse + M, M);
    k_gemm_max<<<N / 64, 256, 0, stream>>>(feat, W, bias, scode, rank, (unsigned*)x_out, N);
    k_ln_gelu<<<M, 256, 0, stream>>>((unsigned*)x_out, gamma, beta, M);
}